// Round 2
// baseline (22092.874 us; speedup 1.0000x reference)
//
#include <hip/hip_runtime.h>
#include <hip/hip_bf16.h>

// 2-layer LSTM, persistent cooperative kernel.
// B=16, S=2048, I=256, H=512. Gates [B,4H] = cat(in,h) @ W^T + b.
// Layer0: blocks 0..31, Layer1: blocks 32..63. Each block: 16 hidden units,
// 4 waves (one gate type each), 16 gate cols per wave, weights in VGPRs as
// bf16 MFMA fragments. Cross-group sync: per-step flag counters in ws.

#define BB 16
#define SS 2048
#define II 256
#define HH 512
#define NG0 32
#define NG1 32
#define OUT_H_OFF (BB * SS * HH)            // 16777216
#define OUT_C_OFF (OUT_H_OFF + 2 * BB * HH) // +16384

typedef __bf16 bf16x8_t __attribute__((ext_vector_type(8)));
typedef float f32x4_t __attribute__((ext_vector_type(4)));

__device__ __forceinline__ float sigmoidf_(float x) {
    return 1.f / (1.f + __expf(-x));
}
__device__ __forceinline__ float tanhf_(float x) {
    // 1 - 2/(e^{2x}+1); exact limits at +-inf, ~1ulp from v_exp_f32
    return 1.f - 2.f / (__expf(2.f * x) + 1.f);
}

__device__ __forceinline__ void wait_ge(int* p, int target) {
    while (__hip_atomic_load(p, __ATOMIC_RELAXED, __HIP_MEMORY_SCOPE_AGENT) < target)
        __builtin_amdgcn_s_sleep(1);
}

__device__ __forceinline__ bf16x8_t cvt8(const float* p) {
    f32x4_t a = *reinterpret_cast<const f32x4_t*>(p);
    f32x4_t b = *reinterpret_cast<const f32x4_t*>(p + 4);
    bf16x8_t r;
    r[0] = (__bf16)a[0]; r[1] = (__bf16)a[1];
    r[2] = (__bf16)a[2]; r[3] = (__bf16)a[3];
    r[4] = (__bf16)b[0]; r[5] = (__bf16)b[1];
    r[6] = (__bf16)b[2]; r[7] = (__bf16)b[3];
    return r;
}

__global__ __launch_bounds__(256, 1) void lstm2_persistent(
    const float* __restrict__ x,   // [B][S][I]
    const float* __restrict__ W0,  // [4H][I+H]
    const float* __restrict__ b0,  // [4H]
    const float* __restrict__ W1,  // [4H][2H]
    const float* __restrict__ b1,  // [4H]
    float* __restrict__ out,       // outputs [B][S][H], then h[2][B][H], c[2][B][H]
    int* flag0, int* flag1,        // [S] each, zeroed before launch
    __bf16* h0buf, __bf16* h1buf)  // [2][B][H] parity double buffers
{
    const int tid = threadIdx.x;
    const int w   = tid >> 6;  // wave id == gate type (0:i 1:f 2:g 3:o)
    const int l   = tid & 63;
    const int cc  = l & 15;    // col-in-tile for B-frag; batch row for A-frag
    const int kg  = l >> 4;    // k-group 0..3
    const int ew_b = tid >> 4; // elementwise: batch
    const int ew_u = tid & 15; // elementwise: unit within block

    __shared__ float gate_s[4][16][17];
    __shared__ float c_s[16][17];

    c_s[ew_u][ew_b] = 0.f;  // (ew_u,ew_b) spans 16x16 over 256 threads

    if (blockIdx.x < NG0) {
        // ---------------- layer 0 ----------------
        const int blk   = blockIdx.x;
        const int ubase = blk * 16;
        const int gcol  = w * HH + ubase + cc;           // row of W0
        const float* wrow = W0 + (size_t)gcol * (II + HH);
        bf16x8_t wf[24];
#pragma unroll
        for (int kk = 0; kk < 24; ++kk)
            wf[kk] = cvt8(wrow + kk * 32 + kg * 8);
        const float bias  = b0[gcol];
        const float* xrow = x + (size_t)cc * SS * II;    // batch cc
        __syncthreads();

        for (int t = 0; t < SS; ++t) {
            if (tid == 0) {
                if (t >= 1) wait_ge(flag0 + (t - 1), NG0); // peers' h0[t-1] ready
                if (t >= 2) wait_ge(flag1 + (t - 2), NG1); // h0 parity buffer free
                __threadfence(); // acquire: invalidate caches before data reads
            }
            __syncthreads();

            f32x4_t acc = {0.f, 0.f, 0.f, 0.f};
            const float* xr = xrow + (size_t)t * II;
#pragma unroll
            for (int kk = 0; kk < 8; ++kk) {
                bf16x8_t a = cvt8(xr + kk * 32 + kg * 8);
                acc = __builtin_amdgcn_mfma_f32_16x16x32_bf16(a, wf[kk], acc, 0, 0, 0);
            }
            if (t > 0) {
                const __bf16* hp = h0buf + ((t - 1) & 1) * (BB * HH) + cc * HH + kg * 8;
#pragma unroll
                for (int kk = 8; kk < 24; ++kk) {
                    bf16x8_t a = *reinterpret_cast<const bf16x8_t*>(hp + (kk - 8) * 32);
                    acc = __builtin_amdgcn_mfma_f32_16x16x32_bf16(a, wf[kk], acc, 0, 0, 0);
                }
            }
            // D layout: col = lane&15, row(batch) = (lane>>4)*4 + r
#pragma unroll
            for (int r = 0; r < 4; ++r)
                gate_s[w][cc][kg * 4 + r] = acc[r] + bias;
            __syncthreads();
            {
                const float gi = gate_s[0][ew_u][ew_b];
                const float gf = gate_s[1][ew_u][ew_b];
                const float gg = gate_s[2][ew_u][ew_b];
                const float go = gate_s[3][ew_u][ew_b];
                const float c  = c_s[ew_u][ew_b];
                const float cn = sigmoidf_(gf) * c + sigmoidf_(gi) * tanhf_(gg);
                const float hn = sigmoidf_(go) * tanhf_(cn);
                c_s[ew_u][ew_b] = cn;
                h0buf[(t & 1) * (BB * HH) + ew_b * HH + ubase + ew_u] = (__bf16)hn;
                if (t == SS - 1) {
                    out[OUT_H_OFF + ew_b * HH + ubase + ew_u] = hn;
                    out[OUT_C_OFF + ew_b * HH + ubase + ew_u] = cn;
                }
            }
            __syncthreads(); // drains vmcnt: all h0 stores complete
            if (tid == 0) {
                __threadfence(); // release: make stores device-visible
                __hip_atomic_fetch_add(flag0 + t, 1, __ATOMIC_RELEASE,
                                       __HIP_MEMORY_SCOPE_AGENT);
            }
        }
    } else {
        // ---------------- layer 1 ----------------
        const int blk   = blockIdx.x - NG0;
        const int ubase = blk * 16;
        const int gcol  = w * HH + ubase + cc;           // row of W1
        const float* wrow = W1 + (size_t)gcol * (2 * HH);
        bf16x8_t wf[32];
#pragma unroll
        for (int kk = 0; kk < 32; ++kk)
            wf[kk] = cvt8(wrow + kk * 32 + kg * 8);
        const float bias = b1[gcol];
        __syncthreads();

        for (int t = 0; t < SS; ++t) {
            if (tid == 0) {
                wait_ge(flag0 + t, NG0);                   // h0[t] ready
                if (t >= 1) wait_ge(flag1 + (t - 1), NG1); // peers' h1[t-1] ready
                __threadfence();
            }
            __syncthreads();

            f32x4_t acc = {0.f, 0.f, 0.f, 0.f};
            const __bf16* h0c = h0buf + (t & 1) * (BB * HH) + cc * HH + kg * 8;
#pragma unroll
            for (int kk = 0; kk < 16; ++kk) {
                bf16x8_t a = *reinterpret_cast<const bf16x8_t*>(h0c + kk * 32);
                acc = __builtin_amdgcn_mfma_f32_16x16x32_bf16(a, wf[kk], acc, 0, 0, 0);
            }
            if (t > 0) {
                const __bf16* h1p = h1buf + ((t - 1) & 1) * (BB * HH) + cc * HH + kg * 8;
#pragma unroll
                for (int kk = 16; kk < 32; ++kk) {
                    bf16x8_t a = *reinterpret_cast<const bf16x8_t*>(h1p + (kk - 16) * 32);
                    acc = __builtin_amdgcn_mfma_f32_16x16x32_bf16(a, wf[kk], acc, 0, 0, 0);
                }
            }
#pragma unroll
            for (int r = 0; r < 4; ++r)
                gate_s[w][cc][kg * 4 + r] = acc[r] + bias;
            __syncthreads();
            {
                const float gi = gate_s[0][ew_u][ew_b];
                const float gf = gate_s[1][ew_u][ew_b];
                const float gg = gate_s[2][ew_u][ew_b];
                const float go = gate_s[3][ew_u][ew_b];
                const float c  = c_s[ew_u][ew_b];
                const float cn = sigmoidf_(gf) * c + sigmoidf_(gi) * tanhf_(gg);
                const float hn = sigmoidf_(go) * tanhf_(cn);
                c_s[ew_u][ew_b] = cn;
                h1buf[(t & 1) * (BB * HH) + ew_b * HH + ubase + ew_u] = (__bf16)hn;
                out[((size_t)ew_b * SS + t) * HH + ubase + ew_u] = hn;
                if (t == SS - 1) {
                    out[OUT_H_OFF + (BB + ew_b) * HH + ubase + ew_u] = hn;
                    out[OUT_C_OFF + (BB + ew_b) * HH + ubase + ew_u] = cn;
                }
            }
            __syncthreads();
            if (tid == 0) {
                __threadfence();
                __hip_atomic_fetch_add(flag1 + t, 1, __ATOMIC_RELEASE,
                                       __HIP_MEMORY_SCOPE_AGENT);
            }
        }
    }
}

extern "C" void kernel_launch(void* const* d_in, const int* in_sizes, int n_in,
                              void* d_out, int out_size, void* d_ws, size_t ws_size,
                              hipStream_t stream) {
    const float* x  = (const float*)d_in[0];
    const float* W0 = (const float*)d_in[1];
    const float* b0 = (const float*)d_in[2];
    const float* W1 = (const float*)d_in[3];
    const float* b1 = (const float*)d_in[4];
    float* out = (float*)d_out;

    char* ws = (char*)d_ws;
    int* flag0 = (int*)ws;                    // S ints
    int* flag1 = (int*)(ws + SS * 4);         // S ints
    __bf16* h0buf = (__bf16*)(ws + 16384);                    // 2*B*H bf16
    __bf16* h1buf = (__bf16*)(ws + 16384 + 2 * BB * HH * 2);  // 2*B*H bf16

    // zero the flag counters (ws is poisoned 0xAA before every timed launch)
    hipMemsetAsync(ws, 0, 16384, stream);

    hipLaunchKernelGGL(lstm2_persistent, dim3(NG0 + NG1), dim3(256), 0, stream,
                       x, W0, b0, W1, b1, out, flag0, flag1, h0buf, h1buf);
}

// Round 3
// 21258.707 us; speedup vs baseline: 1.0392x; 1.0392x over previous
//
#include <hip/hip_runtime.h>
#include <hip/hip_bf16.h>

// 2-layer LSTM, persistent pipelined kernel, fence-free coherent handoff.
// B=16, S=2048, I=256, H=512. Layer0: blocks 0..31, Layer1: blocks 32..63.
// Each block: 16 hidden units, 4 waves (one gate each), weights in VGPRs.
// h-state crosses XCDs via relaxed agent-scope (sc0 sc1) atomics = LLC
// coherence point; NO __threadfence (cache-wide inv/wb) anywhere.
// Flags: per-block monotonic step counters, store + wave-parallel poll.

#define BB 16
#define SS 2048
#define II 256
#define HH 512
#define NG0 32
#define NG1 32
#define BHH (BB * HH)
#define OUT_H_OFF (BB * SS * HH)
#define OUT_C_OFF (OUT_H_OFF + 2 * BB * HH)

typedef __bf16 bf16x8_t __attribute__((ext_vector_type(8)));
typedef float f32x4_t __attribute__((ext_vector_type(4)));

union b128u { uint64_t u[2]; bf16x8_t v; };

__device__ __forceinline__ float sigmoidf_(float x) { return 1.f / (1.f + __expf(-x)); }
__device__ __forceinline__ float tanhf_(float x) { return 1.f - 2.f / (__expf(2.f * x) + 1.f); }

// coherence-point (agent-scope) accessors: global_load/store ... sc0 sc1
__device__ __forceinline__ uint64_t cload64(const void* p) {
    return __hip_atomic_load((const uint64_t*)p, __ATOMIC_RELAXED, __HIP_MEMORY_SCOPE_AGENT);
}
__device__ __forceinline__ bf16x8_t cload_frag(const __bf16* p) {
    b128u r;
    r.u[0] = cload64(p);
    r.u[1] = cload64(p + 4);
    return r.v;
}
__device__ __forceinline__ void cstore_bf16(__bf16* p, float v) {
    __bf16 b = (__bf16)v;
    unsigned short u;
    __builtin_memcpy(&u, &b, 2);
    __hip_atomic_store((unsigned short*)p, u, __ATOMIC_RELAXED, __HIP_MEMORY_SCOPE_AGENT);
}

// wave-parallel wait: lanes 0..31 poll f0[lane] >= T0, lanes 32..63 poll f1[lane-32] >= T1
__device__ __forceinline__ void spin2(const int* f0, int T0, const int* f1, int T1) {
    const int lidx = threadIdx.x & 63;
    const int* p = (lidx < 32) ? (f0 + lidx) : (f1 + (lidx - 32));
    const int tgt = (lidx < 32) ? T0 : T1;
    while (true) {
        int v = __hip_atomic_load(p, __ATOMIC_RELAXED, __HIP_MEMORY_SCOPE_AGENT);
        if (__all(v >= tgt)) break;
    }
    __builtin_amdgcn_sched_barrier(0);
    asm volatile("" ::: "memory");
}

__device__ __forceinline__ bf16x8_t cvt8(const float* p) {
    f32x4_t a = *reinterpret_cast<const f32x4_t*>(p);
    f32x4_t b = *reinterpret_cast<const f32x4_t*>(p + 4);
    bf16x8_t r;
    r[0] = (__bf16)a[0]; r[1] = (__bf16)a[1];
    r[2] = (__bf16)a[2]; r[3] = (__bf16)a[3];
    r[4] = (__bf16)b[0]; r[5] = (__bf16)b[1];
    r[6] = (__bf16)b[2]; r[7] = (__bf16)b[3];
    return r;
}

#define MFMA(A, B, C) __builtin_amdgcn_mfma_f32_16x16x32_bf16((A), (B), (C), 0, 0, 0)

__global__ __launch_bounds__(256, 1) void lstm2_persistent(
    const float* __restrict__ x,   // [B][S][I]
    const float* __restrict__ W0,  // [4H][I+H]
    const float* __restrict__ b0,  // [4H]
    const float* __restrict__ W1,  // [4H][2H]
    const float* __restrict__ b1,  // [4H]
    float* __restrict__ out,       // [B][S][H] then h[2][B][H], c[2][B][H]
    int* flag0, int* flag1,        // [32] each: per-block completed-step counters
    __bf16* h0buf, __bf16* h1buf)  // [2][B][H] parity double buffers
{
    const int tid = threadIdx.x;
    const int w   = tid >> 6;  // wave id == gate type (0:i 1:f 2:g 3:o)
    const int l   = tid & 63;
    const int cc  = l & 15;    // B-frag col / A-frag row (batch)
    const int kg  = l >> 4;    // k-group 0..3
    const int ew_b = tid >> 4; // elementwise: batch
    const int ew_u = tid & 15; // elementwise: unit within tile

    __shared__ float gate_s[4][16][17];
    float cstate = 0.f;  // per-thread (ew_b, ew_u) cell state

    if (blockIdx.x < NG0) {
        // ---------------- layer 0 ----------------
        const int blk   = blockIdx.x;
        const int ubase = blk * 16;
        const int gcol  = w * HH + ubase + cc;
        const float* wrow = W0 + (size_t)gcol * (II + HH);
        bf16x8_t wf[24];
#pragma unroll
        for (int kk = 0; kk < 24; ++kk)
            wf[kk] = cvt8(wrow + kk * 32 + kg * 8);
        const float bias  = b0[gcol];
        const float* xrow = x + (size_t)cc * SS * II;  // batch cc
        bf16x8_t xf[8];
#pragma unroll
        for (int kk = 0; kk < 8; ++kk)
            xf[kk] = cvt8(xrow + kk * 32 + kg * 8);    // t = 0 prefetch
        __syncthreads();

        for (int t = 0; t < SS; ++t) {
            // x-part: no dependence on peers — compute before waiting
            f32x4_t a0 = {0.f,0.f,0.f,0.f}, a1 = a0, a2 = a0, a3 = a0;
            a0 = MFMA(xf[0], wf[0], a0); a1 = MFMA(xf[1], wf[1], a1);
            a2 = MFMA(xf[2], wf[2], a2); a3 = MFMA(xf[3], wf[3], a3);
            a0 = MFMA(xf[4], wf[4], a0); a1 = MFMA(xf[5], wf[5], a1);
            a2 = MFMA(xf[6], wf[6], a2); a3 = MFMA(xf[7], wf[7], a3);

            // peers' h0[t-1] ready: flag0 >= t; slot (t&1) free: flag1 >= t-1
            spin2(flag0, t, flag1, t - 1);

            if (t > 0) {
                const __bf16* hp = h0buf + ((t - 1) & 1) * BHH + cc * HH + kg * 8;
#pragma unroll
                for (int kk = 0; kk < 16; kk += 4) {
                    a0 = MFMA(cload_frag(hp + (kk + 0) * 32), wf[8 + kk + 0], a0);
                    a1 = MFMA(cload_frag(hp + (kk + 1) * 32), wf[8 + kk + 1], a1);
                    a2 = MFMA(cload_frag(hp + (kk + 2) * 32), wf[8 + kk + 2], a2);
                    a3 = MFMA(cload_frag(hp + (kk + 3) * 32), wf[8 + kk + 3], a3);
                }
            }
            f32x4_t acc = (a0 + a1) + (a2 + a3);
#pragma unroll
            for (int r = 0; r < 4; ++r)
                gate_s[w][cc][kg * 4 + r] = acc[r] + bias;

            // prefetch next step's x while others finish / barrier
            if (t + 1 < SS) {
                const float* xr = xrow + (size_t)(t + 1) * II;
#pragma unroll
                for (int kk = 0; kk < 8; ++kk)
                    xf[kk] = cvt8(xr + kk * 32 + kg * 8);
            }
            __syncthreads();
            {
                const float gi = gate_s[0][ew_u][ew_b];
                const float gf = gate_s[1][ew_u][ew_b];
                const float gg = gate_s[2][ew_u][ew_b];
                const float go = gate_s[3][ew_u][ew_b];
                const float cn = sigmoidf_(gf) * cstate + sigmoidf_(gi) * tanhf_(gg);
                const float hn = sigmoidf_(go) * tanhf_(cn);
                cstate = cn;
                cstore_bf16(h0buf + (t & 1) * BHH + ew_b * HH + ubase + ew_u, hn);
                if (t == SS - 1) {
                    out[OUT_H_OFF + ew_b * HH + ubase + ew_u] = hn;
                    out[OUT_C_OFF + ew_b * HH + ubase + ew_u] = cn;
                }
            }
            asm volatile("s_waitcnt vmcnt(0)" ::: "memory"); // h stores at LLC
            __syncthreads();                                 // all waves drained
            if (tid == 0)
                __hip_atomic_store(flag0 + blk, t + 1, __ATOMIC_RELAXED,
                                   __HIP_MEMORY_SCOPE_AGENT);
        }
    } else {
        // ---------------- layer 1 ----------------
        const int blk   = blockIdx.x - NG0;
        const int ubase = blk * 16;
        const int gcol  = w * HH + ubase + cc;
        const float* wrow = W1 + (size_t)gcol * (2 * HH);
        bf16x8_t wf[32];
#pragma unroll
        for (int kk = 0; kk < 32; ++kk)
            wf[kk] = cvt8(wrow + kk * 32 + kg * 8);
        const float bias = b1[gcol];
        __syncthreads();

        for (int t = 0; t < SS; ++t) {
            f32x4_t a0 = {0.f,0.f,0.f,0.f}, a1 = a0, a2 = a0, a3 = a0;
            // h1-part first: only needs peers' h1[t-1] (flag1 >= t)
            spin2(flag1, t, flag1, t);
            if (t > 0) {
                const __bf16* h1p = h1buf + ((t - 1) & 1) * BHH + cc * HH + kg * 8;
#pragma unroll
                for (int kk = 0; kk < 16; kk += 4) {
                    a0 = MFMA(cload_frag(h1p + (kk + 0) * 32), wf[16 + kk + 0], a0);
                    a1 = MFMA(cload_frag(h1p + (kk + 1) * 32), wf[16 + kk + 1], a1);
                    a2 = MFMA(cload_frag(h1p + (kk + 2) * 32), wf[16 + kk + 2], a2);
                    a3 = MFMA(cload_frag(h1p + (kk + 3) * 32), wf[16 + kk + 3], a3);
                }
            }
            // h0[t] ready: flag0 >= t+1
            spin2(flag0, t + 1, flag0, t + 1);
            {
                const __bf16* h0c = h0buf + (t & 1) * BHH + cc * HH + kg * 8;
#pragma unroll
                for (int kk = 0; kk < 16; kk += 4) {
                    a0 = MFMA(cload_frag(h0c + (kk + 0) * 32), wf[kk + 0], a0);
                    a1 = MFMA(cload_frag(h0c + (kk + 1) * 32), wf[kk + 1], a1);
                    a2 = MFMA(cload_frag(h0c + (kk + 2) * 32), wf[kk + 2], a2);
                    a3 = MFMA(cload_frag(h0c + (kk + 3) * 32), wf[kk + 3], a3);
                }
            }
            f32x4_t acc = (a0 + a1) + (a2 + a3);
#pragma unroll
            for (int r = 0; r < 4; ++r)
                gate_s[w][cc][kg * 4 + r] = acc[r] + bias;
            __syncthreads();
            {
                const float gi = gate_s[0][ew_u][ew_b];
                const float gf = gate_s[1][ew_u][ew_b];
                const float gg = gate_s[2][ew_u][ew_b];
                const float go = gate_s[3][ew_u][ew_b];
                const float cn = sigmoidf_(gf) * cstate + sigmoidf_(gi) * tanhf_(gg);
                const float hn = sigmoidf_(go) * tanhf_(cn);
                cstate = cn;
                cstore_bf16(h1buf + (t & 1) * BHH + ew_b * HH + ubase + ew_u, hn);
                out[((size_t)ew_b * SS + t) * HH + ubase + ew_u] = hn;  // plain, cached
                if (t == SS - 1) {
                    out[OUT_H_OFF + (BB + ew_b) * HH + ubase + ew_u] = hn;
                    out[OUT_C_OFF + (BB + ew_b) * HH + ubase + ew_u] = cn;
                }
            }
            asm volatile("s_waitcnt vmcnt(0)" ::: "memory");
            __syncthreads();
            if (tid == 0)
                __hip_atomic_store(flag1 + blk, t + 1, __ATOMIC_RELAXED,
                                   __HIP_MEMORY_SCOPE_AGENT);
        }
    }
}

extern "C" void kernel_launch(void* const* d_in, const int* in_sizes, int n_in,
                              void* d_out, int out_size, void* d_ws, size_t ws_size,
                              hipStream_t stream) {
    const float* x  = (const float*)d_in[0];
    const float* W0 = (const float*)d_in[1];
    const float* b0 = (const float*)d_in[2];
    const float* W1 = (const float*)d_in[3];
    const float* b1 = (const float*)d_in[4];
    float* out = (float*)d_out;

    char* ws = (char*)d_ws;
    int* flag0 = (int*)ws;             // 32 ints
    int* flag1 = (int*)(ws + 128);     // 32 ints
    __bf16* h0buf = (__bf16*)(ws + 4096);          // 2*B*H bf16 = 32 KB
    __bf16* h1buf = (__bf16*)(ws + 4096 + 32768);  // 2*B*H bf16 = 32 KB

    hipMemsetAsync(ws, 0, 256, stream);  // zero flag counters only

    hipLaunchKernelGGL(lstm2_persistent, dim3(NG0 + NG1), dim3(256), 0, stream,
                       x, W0, b0, W1, b1, out, flag0, flag1, h0buf, h1buf);
}